// Round 19
// baseline (9.921 us; speedup 1.0000x reference)
//
#include <hip/hip_runtime.h>
#include <math.h>

#define HH 512
#define WW 512
#define NG 1000
#define NCH 125  // NG/8
#define STEP (1.0f / 511.0f)

// Early-exit threshold: clip saturates at 1.0. Accumulation is monotone
// (every term e*c >= 0), so measured partial > THR => true sum > 1 => final
// clipped value == 1 exactly (1.10/1.04 > 1 covers Schraudolph's ~+/-3%).
#define SAT_THR 1.10f
// Contribution-class cutoff: key = min(cr,cg,cb)*sx*sy; ~top 20% first.
#define KEY_CUT 0.18f

// Schraudolph exp2 bias: 127*2^23 - 366393 (centers rel err to ~+/-3%).
#define SCH_BIAS 1064986823.0f
// 2^11.5 — folded into rotation rows so a'^2 = a^2 * 2^23.
#define SCALE23 2896.309376f

__device__ __forceinline__ float clamp01(float v) {
    return fminf(fmaxf(v, 0.0f), 1.0f);
}

__device__ __forceinline__ float bits2e(float s) {
    return __uint_as_float((unsigned int)s);
}

// r18 structure (full-row 512-thread blocks, quadratic-in-t trick,
// double-buffered hot loop) + minimal 2-class contribution ordering:
// big*bright gaussians scattered to the FRONT of the LDS arrays so the
// per-wave early exit fires after ~tens instead of ~210 gaussians.
// Rank = 2 ballots/thread-chunk + a 32-counter serial scan on thread 0
// (~0.2 us). Result is permutation-invariant (monotone terms).
__global__ __launch_bounds__(512, 4) void gs_fused(
        const float* __restrict__ pos,
        const float* __restrict__ sc,
        const float* __restrict__ rot,
        const float* __restrict__ col,
        const float* __restrict__ op,
        float* __restrict__ out) {
    __shared__ __align__(16) float sD[NCH + 2][6][8];  // 24.4 KB
    __shared__ int wcnt[2][8][2];   // [chunk][wave][class]
    __shared__ int woff[2][8][2];

    const int tid  = threadIdx.x;
    const int lane = tid & 63;
    const int wav  = tid >> 6;
    const unsigned long long ltmask = (1ull << lane) - 1ull;
    const int row = blockIdx.x;
    const float y = (float)row * STEP;
    const float K = 0.84932180f;  // sqrt(0.5 * log2(e))

    float rs0[2], rc1[2], rc2[2], rcr[2], rcg[2], rcb[2];
    int   rcl[2], rpre[2];

#pragma unroll
    for (int j = 0; j < 2; ++j) {
        const int g = tid + j * 512;
        const bool valid = g < NG;
        int cl = 1;
        if (valid) {
            const float px = pos[2 * g + 0];
            const float py = pos[2 * g + 1];
            const float sx = fabsf(sc[2 * g + 0]) + 1e-6f;
            const float sy = fabsf(sc[2 * g + 1]) + 1e-6f;
            const float r  = rot[g];
            const float cth = __cosf(r);
            const float sth = __sinf(r);
            const float isx = SCALE23 * K / sx;
            const float isy = SCALE23 * K / sy;
            const float rxx = cth * isx;
            const float rxy = sth * isx;
            const float ryx = -sth * isy;
            const float ryy = cth * isy;
            const float ox = rxx * px + rxy * py;
            const float oy = ryx * px + ryy * py;
            const float a0 = fmaf(rxy, y, -ox);
            const float b0 = fmaf(ryy, y, -oy);
            const float da = rxx * STEP;
            const float db = ryx * STEP;
            rs0[j] = fmaf(-a0, a0, fmaf(-b0, b0, SCH_BIAS));
            rc1[j] = -2.0f * fmaf(a0, da, b0 * db);
            rc2[j] = -fmaf(da, da, db * db);
            const float so = 1.0f / (1.0f + __expf(-op[g]));
            const float cr = so / (1.0f + __expf(-col[3 * g + 0]));
            const float cg = so / (1.0f + __expf(-col[3 * g + 1]));
            const float cb = so / (1.0f + __expf(-col[3 * g + 2]));
            rcr[j] = cr; rcg[j] = cg; rcb[j] = cb;
            const float key = fminf(cr, fminf(cg, cb)) * sx * sy;
            cl = key > KEY_CUT ? 0 : 1;
        }
        rcl[j] = cl;
        const unsigned long long m0 = __ballot(valid && cl == 0);
        const unsigned long long m1 = __ballot(valid && cl == 1);
        if (lane == 0) {
            wcnt[j][wav][0] = __popcll(m0);
            wcnt[j][wav][1] = __popcll(m1);
        }
        rpre[j] = (int)__popcll((cl == 0 ? m0 : m1) & ltmask);
    }
    __syncthreads();

    if (tid == 0) {
        int run = 0;
        for (int c = 0; c < 2; ++c)
            for (int j = 0; j < 2; ++j)
                for (int w = 0; w < 8; ++w) {
                    woff[j][w][c] = run;
                    run += wcnt[j][w][c];
                }
    }
    __syncthreads();

#pragma unroll
    for (int j = 0; j < 2; ++j) {
        const int g = tid + j * 512;
        if (g < NG) {
            const int rank = woff[j][wav][rcl[j]] + rpre[j];
            const int ch = rank >> 3;
            const int k  = rank & 7;
            sD[ch][0][k] = rs0[j];
            sD[ch][1][k] = rc1[j];
            sD[ch][2][k] = rc2[j];
            sD[ch][3][k] = rcr[j];
            sD[ch][4][k] = rcg[j];
            sD[ch][5][k] = rcb[j];
        }
    }
    __syncthreads();

    const float t  = (float)tid;
    const float t2 = t * t;

    float aR = 0.f, aG = 0.f, aB = 0.f;

#define LOADCH(P, ch)                                  \
    P##S0a = *(const float4*)&sD[ch][0][0];            \
    P##S0b = *(const float4*)&sD[ch][0][4];            \
    P##C1a = *(const float4*)&sD[ch][1][0];            \
    P##C1b = *(const float4*)&sD[ch][1][4];            \
    P##C2a = *(const float4*)&sD[ch][2][0];            \
    P##C2b = *(const float4*)&sD[ch][2][4];            \
    P##CRa = *(const float4*)&sD[ch][3][0];            \
    P##CRb = *(const float4*)&sD[ch][3][4];            \
    P##CGa = *(const float4*)&sD[ch][4][0];            \
    P##CGb = *(const float4*)&sD[ch][4][4];            \
    P##CBa = *(const float4*)&sD[ch][5][0];            \
    P##CBb = *(const float4*)&sD[ch][5][4];

#define ACC1(S0, C1, C2, CR, CG, CB)                                   \
    {                                                                  \
        const float e = bits2e(fmaf(t2, (C2), fmaf(t, (C1), (S0))));   \
        aR = fmaf(e, (CR), aR);                                        \
        aG = fmaf(e, (CG), aG);                                        \
        aB = fmaf(e, (CB), aB);                                        \
    }

#define ACC8(P)                                                        \
    ACC1(P##S0a.x, P##C1a.x, P##C2a.x, P##CRa.x, P##CGa.x, P##CBa.x)   \
    ACC1(P##S0a.y, P##C1a.y, P##C2a.y, P##CRa.y, P##CGa.y, P##CBa.y)   \
    ACC1(P##S0a.z, P##C1a.z, P##C2a.z, P##CRa.z, P##CGa.z, P##CBa.z)   \
    ACC1(P##S0a.w, P##C1a.w, P##C2a.w, P##CRa.w, P##CGa.w, P##CBa.w)   \
    ACC1(P##S0b.x, P##C1b.x, P##C2b.x, P##CRb.x, P##CGb.x, P##CBb.x)   \
    ACC1(P##S0b.y, P##C1b.y, P##C2b.y, P##CRb.y, P##CGb.y, P##CBb.y)   \
    ACC1(P##S0b.z, P##C1b.z, P##C2b.z, P##CRb.z, P##CGb.z, P##CBb.z)   \
    ACC1(P##S0b.w, P##C1b.w, P##C2b.w, P##CRb.w, P##CGb.w, P##CBb.w)

    float4 aS0a, aS0b, aC1a, aC1b, aC2a, aC2b, aCRa, aCRb, aCGa, aCGb, aCBa, aCBb;
    float4 bS0a, bS0b, bC1a, bC1b, bC2a, bC2b, bCRa, bCRb, bCGa, bCGb, bCBa, bCBb;

    LOADCH(a, 0)
    for (int ch = 0; ch < NCH; ch += 2) {
        LOADCH(b, ch + 1)          // prefetch BEFORE the exit check
        ACC8(a)
        if (__all(fminf(fminf(aR, aG), aB) > SAT_THR) || ch + 1 >= NCH) {
            break;
        }
        LOADCH(a, ch + 2)          // prefetch BEFORE the exit check
        ACC8(b)
        if (__all(fminf(fminf(aR, aG), aB) > SAT_THR)) {
            break;
        }
    }
#undef ACC8
#undef ACC1
#undef LOADCH

    const int idx = row * WW + tid;
    const int hw = HH * WW;
    out[0 * hw + idx] = clamp01(aR);
    out[1 * hw + idx] = clamp01(aG);
    out[2 * hw + idx] = clamp01(aB);
}

extern "C" void kernel_launch(void* const* d_in, const int* in_sizes, int n_in,
                              void* d_out, int out_size, void* d_ws, size_t ws_size,
                              hipStream_t stream) {
    const float* pos = (const float*)d_in[0];  // [1000,2]
    const float* sc  = (const float*)d_in[1];  // [1000,2]
    const float* rot = (const float*)d_in[2];  // [1000]
    const float* col = (const float*)d_in[3];  // [1000,3]
    const float* op  = (const float*)d_in[4];  // [1000]
    float* out = (float*)d_out;                // [3,512,512]

    gs_fused<<<HH, 512, 0, stream>>>(pos, sc, rot, col, op, out);
}